// Round 11
// baseline (154.533 us; speedup 1.0000x reference)
//
#include <hip/hip_runtime.h>
#include <stdint.h>

typedef __attribute__((ext_vector_type(4))) float f32x4;
typedef __attribute__((ext_vector_type(8))) short bf16x8;
typedef __attribute__((ext_vector_type(4))) unsigned short u16x4;
typedef __attribute__((ext_vector_type(4))) unsigned int u32x4;

constexpr int cB = 4, cS = 4096, cD = 1024, cH = 1024;
constexpr int cM = cB * cS;      // 16384
constexpr int cK = cD;           // 1024
constexpr int NCH = 64;          // scan chunks along S
constexpr int CLEN = cS / NCH;   // 64

__device__ __forceinline__ unsigned short f2bf(float f) {
  union { float f; uint32_t u; } v; v.f = f;
  uint32_t r = v.u + 0x7FFFu + ((v.u >> 16) & 1u);
  return (unsigned short)(r >> 16);
}
__device__ __forceinline__ float bf2f(unsigned short h) {
  union { float f; uint32_t u; } v; v.u = ((uint32_t)h) << 16;
  return v.f;
}

// fp32 -> bf16 round (x and W; residual terms dropped — R5/R6 error model,
// measured absmax 0.0156 vs threshold 0.0619)
__global__ void round_kernel(const float* __restrict__ src,
                             unsigned short* __restrict__ hi) {
  int i = (blockIdx.x * blockDim.x + threadIdx.x) * 4;
  f32x4 x = *(const f32x4*)(src + i);
  u16x4 h;
#pragma unroll
  for (int j = 0; j < 4; ++j) h[j] = f2bf(x[j]);
  *(u16x4*)(hi + i) = h;
}

// ======= fused GEMM + chunk-scan epilogue.
// R8: dual-stream (Wz+Wh). R9: in-register chunk (P,Q). R10: packed cg writes.
// R11: T3-minimum 2-phase pipeline — BK=32 double-buffer (2x24KiB, same 48KiB
// total), STAGE(t+1) issued BEFORE compute(t), one vmcnt(0)+barrier per iter.
// BK=32 rows are 64B -> swizzle is col ^= ((row>>1)&3)<<4 (both sides, rule 21).
constexpr int BM = 128, BN = 128, BK = 32;
constexpr int NT = cK / BK;   // 32

#define BARRIER() asm volatile("s_barrier" ::: "memory")
#define WAITVM0() asm volatile("s_waitcnt vmcnt(0)" ::: "memory")

// stage 64 rows x 32 cols bf16 (4 KiB) with pre-swizzled source (rule #21)
__device__ __forceinline__ void stage64x32(const unsigned short* __restrict__ g,
                                           unsigned short* lds, int tid) {
  const int row  = tid >> 2;                                    // 0..63
  const int scol = ((tid & 3) * 8) ^ (((row >> 1) & 3) << 3);   // element idx
  __builtin_amdgcn_global_load_lds(
      (const __attribute__((address_space(1))) void*)(g + (size_t)row * cK + scol),
      (__attribute__((address_space(3))) void*)(lds + (size_t)tid * 8), 16, 0, 0);
}

__global__ __launch_bounds__(256, 2) void gemm_kernel(
    const unsigned short* __restrict__ xh,
    const unsigned short* __restrict__ wwh,   // [Wz(1024 rows); Wh(1024 rows)]
    const float* __restrict__ bz, const float* __restrict__ bhv,
    unsigned int* __restrict__ cgbuf,
    float* __restrict__ Pb, float* __restrict__ Qb)
{
  __shared__ unsigned short Ab[2][BM * BK];   // 2 x 8 KiB
  __shared__ unsigned short Bz[2][BN * BK];   // 2 x 8 KiB
  __shared__ unsigned short Bh[2][BN * BK];   // 2 x 8 KiB (48 KiB total)
  const int tid  = threadIdx.x;
  const int lane = tid & 63;
  const int wv   = tid >> 6;
  const int wr   = wv >> 1, wc = wv & 1;

  // XCD-chunked mapping (R7: FETCH 245->83 MB). 1024 blocks, 128/XCD.
  const int bid = blockIdx.x;          // 0..1023
  const int xcd = bid & 7;
  const int idx = bid >> 3;            // 0..127 within XCD
  const int mt  = xcd * 16 + (idx >> 3);   // 16 mt-rows per XCD, nt-fastest
  const int nt  = idx & 7;
  const int m0 = mt * BM, n0 = nt * BN;
  const int fr = lane & 15, fq = lane >> 4;

  f32x4 accz[4][4] = {};
  f32x4 acch[4][4] = {};

  const unsigned short* gA = xh  + (size_t)m0 * cK;
  const unsigned short* gZ = wwh + (size_t)n0 * cK;
  const unsigned short* gH = wwh + (size_t)(cH + n0) * cK;

  // prologue: stage tile 0 into buf 0
  stage64x32(gA, Ab[0], tid);
  stage64x32(gA + (size_t)64 * cK, Ab[0] + 2048, tid);
  stage64x32(gZ, Bz[0], tid);
  stage64x32(gZ + (size_t)64 * cK, Bz[0] + 2048, tid);
  stage64x32(gH, Bh[0], tid);
  stage64x32(gH + (size_t)64 * cK, Bh[0] + 2048, tid);
  WAITVM0();
  BARRIER();

#pragma unroll 2
  for (int t = 0; t < NT; ++t) {
    const int cur = t & 1, nxt = cur ^ 1;
    const int kn = (t + 1) * BK;
    // issue next tile's stage FIRST — latency hides under this tile's compute
    if (t + 1 < NT) {
      stage64x32(gA + kn, Ab[nxt], tid);
      stage64x32(gA + (size_t)64 * cK + kn, Ab[nxt] + 2048, tid);
      stage64x32(gZ + kn, Bz[nxt], tid);
      stage64x32(gZ + (size_t)64 * cK + kn, Bz[nxt] + 2048, tid);
      stage64x32(gH + kn, Bh[nxt], tid);
      stage64x32(gH + (size_t)64 * cK + kn, Bh[nxt] + 2048, tid);
    }
    // compute current tile
    bf16x8 fa[4], fz[4], fh[4];
#pragma unroll
    for (int i = 0; i < 4; ++i) {
      const int ar = wr * 64 + i * 16 + fr;
      const int ca = (fq * 8) ^ (((ar >> 1) & 3) << 3);   // element idx
      fa[i] = *(const bf16x8*)(Ab[cur] + ar * 32 + ca);
      const int br = wc * 64 + i * 16 + fr;
      const int cb = (fq * 8) ^ (((br >> 1) & 3) << 3);
      fz[i] = *(const bf16x8*)(Bz[cur] + br * 32 + cb);
      fh[i] = *(const bf16x8*)(Bh[cur] + br * 32 + cb);
    }
#pragma unroll
    for (int i = 0; i < 4; ++i)
#pragma unroll
      for (int j = 0; j < 4; ++j) {
        accz[i][j] = __builtin_amdgcn_mfma_f32_16x16x32_bf16(fa[i], fz[j], accz[i][j], 0, 0, 0);
        acch[i][j] = __builtin_amdgcn_mfma_f32_16x16x32_bf16(fa[i], fh[j], acch[i][j], 0, 0, 0);
      }
    WAITVM0();   // next tile landed (all 6 loads)
    BARRIER();   // all waves done reading cur + all stages visible
  }

  // ===== epilogue: packed c/g + in-register chunk scan.
  // wave wr owns chunk ch = (mt&31)*2 + wr of batch b = mt>>5;
  // row-in-chunk t = i*16 + fq*4 + rg.
  const int b  = mt >> 5;
  const int ch = (mt & 31) * 2 + wr;
#pragma unroll
  for (int j = 0; j < 4; ++j) {
    const int n = n0 + wc * 64 + j * 16 + fr;
    const float bz_n = bz[n];
    const float bh_n = bhv[n];
    float psg[4], qsg[4];
#pragma unroll
    for (int i = 0; i < 4; ++i) {
      float p = 1.0f, q = 0.0f;
#pragma unroll
      for (int rg = 0; rg < 4; ++rg) {
        const int m = m0 + wr * 64 + i * 16 + fq * 4 + rg;
        const float kv = accz[i][j][rg] + bz_n;
        const float av = acch[i][j][rg] + bh_n;
        const float c = 1.0f / (1.0f + expf(kv));
        const float g = (av >= 0.0f) ? (av + 0.5f) : (1.0f / (1.0f + expf(-av)));
        cgbuf[(size_t)m * cH + n] = ((uint32_t)f2bf(g) << 16) | (uint32_t)f2bf(c);
        q = c * q + (1.0f - c) * g;   // compose step (c,(1-c)g) ∘ (p,q)
        p = c * p;
      }
      // cross-fq ordered compose (lanes fq*16+fr; partner masks 16,32)
      float pp = __shfl_xor(p, 16), qq = __shfl_xor(q, 16);
      if (fq & 1) { q = q + p * qq; } else { q = qq + pp * q; }
      p = p * pp;
      pp = __shfl_xor(p, 32); qq = __shfl_xor(q, 32);
      if (fq & 2) { q = q + p * qq; } else { q = qq + pp * q; }
      p = p * pp;
      psg[i] = p; qsg[i] = q;
    }
    float P = psg[0], Q = qsg[0];
#pragma unroll
    for (int i = 1; i < 4; ++i) { Q = qsg[i] + psg[i] * Q; P = psg[i] * P; }
    if (fq == 0) {
      const size_t o = ((size_t)b * NCH + ch) * cH + n;
      Pb[o] = P; Qb[o] = Q;
    }
  }
}

// ======= wave-parallel chunk-prefix: Kogge-Stone compose-scan over 64 chunks.
__global__ void scan_prefix_kernel(const float* __restrict__ h0,
                                   const float* __restrict__ Pb, const float* __restrict__ Qb,
                                   float* __restrict__ hin) {
  const int wid  = (blockIdx.x * blockDim.x + threadIdx.x) >> 6;  // 0..4095
  const int lane = threadIdx.x & 63;
  const int b = wid >> 10, h = wid & 1023;
  const size_t o = ((size_t)b * NCH + lane) * cH + h;
  float P = Pb[o], Q = Qb[o];
#pragma unroll
  for (int off = 1; off < 64; off <<= 1) {
    float Po = __shfl_up(P, off), Qo = __shfl_up(Q, off);
    if (lane >= off) { Q = P * Qo + Q; P = P * Po; }
  }
  float Pe = __shfl_up(P, 1), Qe = __shfl_up(Q, 1);
  if (lane == 0) { Pe = 1.0f; Qe = 0.0f; }
  const float x = h0[b * cH + h];
  const float h0g = (x >= 0.0f) ? (x + 0.5f) : (1.0f / (1.0f + expf(-x)));  // g(h0)
  hin[o] = Pe * h0g + Qe;
}

__global__ void scan_write_kernel(const unsigned int* __restrict__ cg,
                                  const float* __restrict__ hin, float* __restrict__ out) {
  const int bc = blockIdx.x;
  const int b = bc / NCH, ch = bc % NCH;
  const int h4 = threadIdx.x * 4;
  f32x4 hc = *(const f32x4*)(hin + ((size_t)b * NCH + ch) * cH + h4);
  size_t base = ((size_t)b * cS + (size_t)ch * CLEN) * cH + h4;
#pragma unroll 4
  for (int i = 0; i < CLEN; ++i) {
    u32x4 v = *(const u32x4*)(cg + base + (size_t)i * cH);
#pragma unroll
    for (int j = 0; j < 4; ++j) {
      const float c = bf2f((unsigned short)(v[j] & 0xFFFFu));
      const float g = bf2f((unsigned short)(v[j] >> 16));
      hc[j] = c * hc[j] + (1.0f - c) * g;
    }
    *(f32x4*)(out + base + (size_t)i * cH) = hc;
  }
  if (ch == NCH - 1) {
    *(f32x4*)(out + (size_t)cM * cH + (size_t)b * cH + h4) = hc;
  }
}

extern "C" void kernel_launch(void* const* d_in, const int* in_sizes, int n_in,
                              void* d_out, int out_size, void* d_ws, size_t ws_size,
                              hipStream_t stream) {
  const float* x   = (const float*)d_in[0];
  const float* h0  = (const float*)d_in[1];
  const float* Wz  = (const float*)d_in[2];
  const float* bz  = (const float*)d_in[3];
  const float* Wh  = (const float*)d_in[4];
  const float* bh  = (const float*)d_in[5];

  char* ws = (char*)d_ws;
  unsigned short* xh   = (unsigned short*)(ws);                         // 32 MiB
  unsigned short* wwh  = (unsigned short*)(ws + (((size_t)32) << 20));  // 4 MiB
  unsigned int*   cgbuf= (unsigned int*)(ws + (((size_t)40) << 20));    // 64 MiB
  float* Pb   = (float*)(ws + (((size_t)104) << 20));                   // 1 MiB
  float* Qb   = (float*)(ws + (((size_t)105) << 20));                   // 1 MiB
  float* hin  = (float*)(ws + (((size_t)106) << 20));                   // 1 MiB
  float* out  = (float*)d_out;

  round_kernel<<<cM * cK / 1024, 256, 0, stream>>>(x, xh);
  round_kernel<<<cH * cK / 1024, 256, 0, stream>>>(Wz, wwh);
  round_kernel<<<cH * cK / 1024, 256, 0, stream>>>(Wh, wwh + (size_t)cH * cK);
  gemm_kernel<<<(cM / BM) * (cH / BN), 256, 0, stream>>>(xh, wwh, bz, bh, cgbuf, Pb, Qb);
  scan_prefix_kernel<<<cB * cH * 64 / 256, 256, 0, stream>>>(h0, Pb, Qb, hin);
  scan_write_kernel<<<cB * NCH, 256, 0, stream>>>(cgbuf, hin, out);
}

// Round 12
// 138.943 us; speedup vs baseline: 1.1122x; 1.1122x over previous
//
#include <hip/hip_runtime.h>
#include <stdint.h>

typedef __attribute__((ext_vector_type(4))) float f32x4;
typedef __attribute__((ext_vector_type(8))) short bf16x8;
typedef __attribute__((ext_vector_type(4))) unsigned short u16x4;
typedef __attribute__((ext_vector_type(4))) unsigned int u32x4;

constexpr int cB = 4, cS = 4096, cD = 1024, cH = 1024;
constexpr int cM = cB * cS;      // 16384
constexpr int cK = cD;           // 1024
constexpr int NCH = 64;          // scan chunks along S
constexpr int CLEN = cS / NCH;   // 64

__device__ __forceinline__ unsigned short f2bf(float f) {
  union { float f; uint32_t u; } v; v.f = f;
  uint32_t r = v.u + 0x7FFFu + ((v.u >> 16) & 1u);
  return (unsigned short)(r >> 16);
}
__device__ __forceinline__ float bf2f(unsigned short h) {
  union { float f; uint32_t u; } v; v.u = ((uint32_t)h) << 16;
  return v.f;
}

// fp32 -> bf16 round (W only now; x is rounded in-GEMM — R12)
__global__ void round_kernel(const float* __restrict__ src,
                             unsigned short* __restrict__ hi) {
  int i = (blockIdx.x * blockDim.x + threadIdx.x) * 4;
  f32x4 x = *(const f32x4*)(src + i);
  u16x4 h;
#pragma unroll
  for (int j = 0; j < 4; ++j) h[j] = f2bf(x[j]);
  *(u16x4*)(hi + i) = h;
}

// ======= fused GEMM + chunk-scan epilogue (R10 structure, verbatim).
// R8: dual-stream (Wz+Wh). R9: in-register chunk (P,Q). R10: packed cg writes.
// R12: A staged from fp32 x with in-kernel f2bf (reg-stage + ds_write to the
// SAME LDS bytes the DMA wrote) -> round_x kernel deleted (-96 MB traffic).
// R11 lesson (3rd pipeline failure): at 2 blocks/CU, inter-block TLP covers
// the drain; keep the simple vmcnt0+barrier per BK=64 tile.
constexpr int BM = 128, BN = 128, BK = 64;

__global__ __launch_bounds__(256, 2) void gemm_kernel(
    const float* __restrict__ xf,
    const unsigned short* __restrict__ wwh,   // [Wz(1024 rows); Wh(1024 rows)]
    const float* __restrict__ bz, const float* __restrict__ bhv,
    unsigned int* __restrict__ cgbuf,
    float* __restrict__ Pb, float* __restrict__ Qb)
{
  __shared__ unsigned short Ah[BM * BK], Bz[BN * BK], Bh[BN * BK];  // 48 KiB
  const int tid  = threadIdx.x;
  const int lane = tid & 63;
  const int wv   = tid >> 6;
  const int wr   = wv >> 1, wc = wv & 1;

  // XCD-chunked mapping (R7: FETCH 245->83 MB). 1024 blocks, 128/XCD.
  const int bid = blockIdx.x;          // 0..1023
  const int xcd = bid & 7;
  const int idx = bid >> 3;            // 0..127 within XCD
  const int mt  = xcd * 16 + (idx >> 3);   // 16 mt-rows per XCD, nt-fastest
  const int nt  = idx & 7;
  const int m0 = mt * BM, n0 = nt * BN;
  const int fr = lane & 15, fq = lane >> 4;

  f32x4 accz[4][4] = {};
  f32x4 acch[4][4] = {};

  // staging: LDS linear dest; source pre-swizzled (rule #21): col ^= (row&7)
  const int srow = tid >> 3;                              // 0..31
  const int scol = (((tid & 7) ^ (srow & 7)) << 3);       // element index

  const float*          gX = xf  + (size_t)m0 * cK;
  const unsigned short* gZ = wwh + (size_t)n0 * cK;
  const unsigned short* gH = wwh + (size_t)(cH + n0) * cK;

  for (int kt = 0; kt < cK / BK; ++kt) {
    const int k0 = kt * BK;
    __syncthreads();
#pragma unroll
    for (int r = 0; r < 4; ++r) {
      const int row = r * 32 + srow;
      const int ldsoff = r * 4096 + tid * 16;
      const size_t goff = (size_t)row * cK + k0 + scol;
      // A: fp32 -> bf16 reg-stage (same source offset, same f2bf, same LDS bytes)
      const f32x4 alo = *(const f32x4*)(gX + goff);
      const f32x4 ahi = *(const f32x4*)(gX + goff + 4);
      u32x4 apk;
      apk[0] = ((uint32_t)f2bf(alo[1]) << 16) | f2bf(alo[0]);
      apk[1] = ((uint32_t)f2bf(alo[3]) << 16) | f2bf(alo[2]);
      apk[2] = ((uint32_t)f2bf(ahi[1]) << 16) | f2bf(ahi[0]);
      apk[3] = ((uint32_t)f2bf(ahi[3]) << 16) | f2bf(ahi[2]);
      *(u32x4*)((char*)Ah + ldsoff) = apk;
      // B: async DMA as before
      __builtin_amdgcn_global_load_lds((const __attribute__((address_space(1))) void*)(gZ + goff),
        (__attribute__((address_space(3))) void*)((char*)Bz + ldsoff), 16, 0, 0);
      __builtin_amdgcn_global_load_lds((const __attribute__((address_space(1))) void*)(gH + goff),
        (__attribute__((address_space(3))) void*)((char*)Bh + ldsoff), 16, 0, 0);
    }
    __syncthreads();
#pragma unroll
    for (int kk = 0; kk < BK / 32; ++kk) {
      bf16x8 fa[4], fz[4], fh[4];
#pragma unroll
      for (int i = 0; i < 4; ++i) {
        const int ar = wr * 64 + i * 16 + fr;
        const int ca = (kk * 64 + fq * 16) ^ ((ar & 7) << 4);   // swizzled read (bytes)
        fa[i] = *(const bf16x8*)((const char*)Ah + ar * 128 + ca);
        const int br = wc * 64 + i * 16 + fr;
        const int cb = (kk * 64 + fq * 16) ^ ((br & 7) << 4);
        fz[i] = *(const bf16x8*)((const char*)Bz + br * 128 + cb);
        fh[i] = *(const bf16x8*)((const char*)Bh + br * 128 + cb);
      }
#pragma unroll
      for (int i = 0; i < 4; ++i)
#pragma unroll
        for (int j = 0; j < 4; ++j) {
          accz[i][j] = __builtin_amdgcn_mfma_f32_16x16x32_bf16(fa[i], fz[j], accz[i][j], 0, 0, 0);
          acch[i][j] = __builtin_amdgcn_mfma_f32_16x16x32_bf16(fa[i], fh[j], acch[i][j], 0, 0, 0);
        }
    }
  }

  // ===== epilogue: packed c/g + in-register chunk scan.
  // wave wr owns chunk ch = (mt&31)*2 + wr of batch b = mt>>5;
  // row-in-chunk t = i*16 + fq*4 + rg.
  const int b  = mt >> 5;
  const int ch = (mt & 31) * 2 + wr;
#pragma unroll
  for (int j = 0; j < 4; ++j) {
    const int n = n0 + wc * 64 + j * 16 + fr;
    const float bz_n = bz[n];
    const float bh_n = bhv[n];
    float psg[4], qsg[4];
#pragma unroll
    for (int i = 0; i < 4; ++i) {
      float p = 1.0f, q = 0.0f;
#pragma unroll
      for (int rg = 0; rg < 4; ++rg) {
        const int m = m0 + wr * 64 + i * 16 + fq * 4 + rg;
        const float kv = accz[i][j][rg] + bz_n;
        const float av = acch[i][j][rg] + bh_n;
        const float c = 1.0f / (1.0f + expf(kv));
        const float g = (av >= 0.0f) ? (av + 0.5f) : (1.0f / (1.0f + expf(-av)));
        cgbuf[(size_t)m * cH + n] = ((uint32_t)f2bf(g) << 16) | (uint32_t)f2bf(c);
        q = c * q + (1.0f - c) * g;   // compose step (c,(1-c)g) ∘ (p,q)
        p = c * p;
      }
      // cross-fq ordered compose (lanes fq*16+fr; partner masks 16,32)
      float pp = __shfl_xor(p, 16), qq = __shfl_xor(q, 16);
      if (fq & 1) { q = q + p * qq; } else { q = qq + pp * q; }
      p = p * pp;
      pp = __shfl_xor(p, 32); qq = __shfl_xor(q, 32);
      if (fq & 2) { q = q + p * qq; } else { q = qq + pp * q; }
      p = p * pp;
      psg[i] = p; qsg[i] = q;
    }
    float P = psg[0], Q = qsg[0];
#pragma unroll
    for (int i = 1; i < 4; ++i) { Q = qsg[i] + psg[i] * Q; P = psg[i] * P; }
    if (fq == 0) {
      const size_t o = ((size_t)b * NCH + ch) * cH + n;
      Pb[o] = P; Qb[o] = Q;
    }
  }
}

// ======= wave-parallel chunk-prefix: Kogge-Stone compose-scan over 64 chunks.
__global__ void scan_prefix_kernel(const float* __restrict__ h0,
                                   const float* __restrict__ Pb, const float* __restrict__ Qb,
                                   float* __restrict__ hin) {
  const int wid  = (blockIdx.x * blockDim.x + threadIdx.x) >> 6;  // 0..4095
  const int lane = threadIdx.x & 63;
  const int b = wid >> 10, h = wid & 1023;
  const size_t o = ((size_t)b * NCH + lane) * cH + h;
  float P = Pb[o], Q = Qb[o];
#pragma unroll
  for (int off = 1; off < 64; off <<= 1) {
    float Po = __shfl_up(P, off), Qo = __shfl_up(Q, off);
    if (lane >= off) { Q = P * Qo + Q; P = P * Po; }
  }
  float Pe = __shfl_up(P, 1), Qe = __shfl_up(Q, 1);
  if (lane == 0) { Pe = 1.0f; Qe = 0.0f; }
  const float x = h0[b * cH + h];
  const float h0g = (x >= 0.0f) ? (x + 0.5f) : (1.0f / (1.0f + expf(-x)));  // g(h0)
  hin[o] = Pe * h0g + Qe;
}

__global__ void scan_write_kernel(const unsigned int* __restrict__ cg,
                                  const float* __restrict__ hin, float* __restrict__ out) {
  const int bc = blockIdx.x;
  const int b = bc / NCH, ch = bc % NCH;
  const int h4 = threadIdx.x * 4;
  f32x4 hc = *(const f32x4*)(hin + ((size_t)b * NCH + ch) * cH + h4);
  size_t base = ((size_t)b * cS + (size_t)ch * CLEN) * cH + h4;
#pragma unroll 4
  for (int i = 0; i < CLEN; ++i) {
    u32x4 v = *(const u32x4*)(cg + base + (size_t)i * cH);
#pragma unroll
    for (int j = 0; j < 4; ++j) {
      const float c = bf2f((unsigned short)(v[j] & 0xFFFFu));
      const float g = bf2f((unsigned short)(v[j] >> 16));
      hc[j] = c * hc[j] + (1.0f - c) * g;
    }
    *(f32x4*)(out + base + (size_t)i * cH) = hc;
  }
  if (ch == NCH - 1) {
    *(f32x4*)(out + (size_t)cM * cH + (size_t)b * cH + h4) = hc;
  }
}

extern "C" void kernel_launch(void* const* d_in, const int* in_sizes, int n_in,
                              void* d_out, int out_size, void* d_ws, size_t ws_size,
                              hipStream_t stream) {
  const float* x   = (const float*)d_in[0];
  const float* h0  = (const float*)d_in[1];
  const float* Wz  = (const float*)d_in[2];
  const float* bz  = (const float*)d_in[3];
  const float* Wh  = (const float*)d_in[4];
  const float* bh  = (const float*)d_in[5];

  char* ws = (char*)d_ws;
  unsigned short* wwh  = (unsigned short*)(ws + (((size_t)32) << 20));  // 4 MiB
  unsigned int*   cgbuf= (unsigned int*)(ws + (((size_t)40) << 20));    // 64 MiB
  float* Pb   = (float*)(ws + (((size_t)104) << 20));                   // 1 MiB
  float* Qb   = (float*)(ws + (((size_t)105) << 20));                   // 1 MiB
  float* hin  = (float*)(ws + (((size_t)106) << 20));                   // 1 MiB
  float* out  = (float*)d_out;

  round_kernel<<<cH * cK / 1024, 256, 0, stream>>>(Wz, wwh);
  round_kernel<<<cH * cK / 1024, 256, 0, stream>>>(Wh, wwh + (size_t)cH * cK);
  gemm_kernel<<<(cM / BM) * (cH / BN), 256, 0, stream>>>(x, wwh, bz, bh, cgbuf, Pb, Qb);
  scan_prefix_kernel<<<cB * cH * 64 / 256, 256, 0, stream>>>(h0, Pb, Qb, hin);
  scan_write_kernel<<<cB * NCH, 256, 0, stream>>>(cgbuf, hin, out);
}

// Round 13
// 138.742 us; speedup vs baseline: 1.1138x; 1.0015x over previous
//
#include <hip/hip_runtime.h>
#include <stdint.h>

typedef __attribute__((ext_vector_type(4))) float f32x4;
typedef __attribute__((ext_vector_type(8))) short bf16x8;
typedef __attribute__((ext_vector_type(4))) unsigned short u16x4;
typedef __attribute__((ext_vector_type(4))) unsigned int u32x4;

constexpr int cB = 4, cS = 4096, cD = 1024, cH = 1024;
constexpr int cM = cB * cS;      // 16384
constexpr int cK = cD;           // 1024
constexpr int NCH = 64;          // scan chunks along S
constexpr int CLEN = cS / NCH;   // 64

__device__ __forceinline__ unsigned short f2bf(float f) {
  union { float f; uint32_t u; } v; v.f = f;
  uint32_t r = v.u + 0x7FFFu + ((v.u >> 16) & 1u);
  return (unsigned short)(r >> 16);
}
__device__ __forceinline__ float bf2f(unsigned short h) {
  union { float f; uint32_t u; } v; v.u = ((uint32_t)h) << 16;
  return v.f;
}

// fp32 -> bf16 round (W only; x is rounded in-GEMM — R12)
__global__ void round_kernel(const float* __restrict__ src,
                             unsigned short* __restrict__ hi) {
  int i = (blockIdx.x * blockDim.x + threadIdx.x) * 4;
  f32x4 x = *(const f32x4*)(src + i);
  u16x4 h;
#pragma unroll
  for (int j = 0; j < 4; ++j) h[j] = f2bf(x[j]);
  *(u16x4*)(hi + i) = h;
}

// ======= fused GEMM + chunk-scan epilogue.
// R8: dual-stream (Wz+Wh). R9: in-register chunk (P,Q). R10: packed cg writes.
// R12: A staged from fp32 x with in-kernel f2bf (round_x deleted).
// R13: B DMAs issued BEFORE the A reg-stage — R12 issued them after, so their
// ~500cyc latency was fully exposed at the closing barrier (gemm 97->130).
// Now the A-path's load+cvt+ds_write work covers the B DMA latency.
constexpr int BM = 128, BN = 128, BK = 64;

__global__ __launch_bounds__(256, 2) void gemm_kernel(
    const float* __restrict__ xf,
    const unsigned short* __restrict__ wwh,   // [Wz(1024 rows); Wh(1024 rows)]
    const float* __restrict__ bz, const float* __restrict__ bhv,
    unsigned int* __restrict__ cgbuf,
    float* __restrict__ Pb, float* __restrict__ Qb)
{
  __shared__ unsigned short Ah[BM * BK], Bz[BN * BK], Bh[BN * BK];  // 48 KiB
  const int tid  = threadIdx.x;
  const int lane = tid & 63;
  const int wv   = tid >> 6;
  const int wr   = wv >> 1, wc = wv & 1;

  // XCD-chunked mapping (R7: FETCH 245->83 MB). 1024 blocks, 128/XCD.
  const int bid = blockIdx.x;          // 0..1023
  const int xcd = bid & 7;
  const int idx = bid >> 3;            // 0..127 within XCD
  const int mt  = xcd * 16 + (idx >> 3);   // 16 mt-rows per XCD, nt-fastest
  const int nt  = idx & 7;
  const int m0 = mt * BM, n0 = nt * BN;
  const int fr = lane & 15, fq = lane >> 4;

  f32x4 accz[4][4] = {};
  f32x4 acch[4][4] = {};

  // staging: LDS linear dest; source pre-swizzled (rule #21): col ^= (row&7)
  const int srow = tid >> 3;                              // 0..31
  const int scol = (((tid & 7) ^ (srow & 7)) << 3);       // element index

  const float*          gX = xf  + (size_t)m0 * cK;
  const unsigned short* gZ = wwh + (size_t)n0 * cK;
  const unsigned short* gH = wwh + (size_t)(cH + n0) * cK;

  for (int kt = 0; kt < cK / BK; ++kt) {
    const int k0 = kt * BK;
    __syncthreads();
    // B DMAs FIRST (R13): latency hides under the A reg-stage below
#pragma unroll
    for (int r = 0; r < 4; ++r) {
      const int row = r * 32 + srow;
      const int ldsoff = r * 4096 + tid * 16;
      const size_t goff = (size_t)row * cK + k0 + scol;
      __builtin_amdgcn_global_load_lds((const __attribute__((address_space(1))) void*)(gZ + goff),
        (__attribute__((address_space(3))) void*)((char*)Bz + ldsoff), 16, 0, 0);
      __builtin_amdgcn_global_load_lds((const __attribute__((address_space(1))) void*)(gH + goff),
        (__attribute__((address_space(3))) void*)((char*)Bh + ldsoff), 16, 0, 0);
    }
    // A: fp32 -> bf16 reg-stage (same f2bf bits as round_x would produce)
#pragma unroll
    for (int r = 0; r < 4; ++r) {
      const int row = r * 32 + srow;
      const int ldsoff = r * 4096 + tid * 16;
      const size_t goff = (size_t)row * cK + k0 + scol;
      const f32x4 alo = *(const f32x4*)(gX + goff);
      const f32x4 ahi = *(const f32x4*)(gX + goff + 4);
      u32x4 apk;
      apk[0] = ((uint32_t)f2bf(alo[1]) << 16) | f2bf(alo[0]);
      apk[1] = ((uint32_t)f2bf(alo[3]) << 16) | f2bf(alo[2]);
      apk[2] = ((uint32_t)f2bf(ahi[1]) << 16) | f2bf(ahi[0]);
      apk[3] = ((uint32_t)f2bf(ahi[3]) << 16) | f2bf(ahi[2]);
      *(u32x4*)((char*)Ah + ldsoff) = apk;
    }
    __syncthreads();
#pragma unroll
    for (int kk = 0; kk < BK / 32; ++kk) {
      bf16x8 fa[4], fz[4], fh[4];
#pragma unroll
      for (int i = 0; i < 4; ++i) {
        const int ar = wr * 64 + i * 16 + fr;
        const int ca = (kk * 64 + fq * 16) ^ ((ar & 7) << 4);   // swizzled read (bytes)
        fa[i] = *(const bf16x8*)((const char*)Ah + ar * 128 + ca);
        const int br = wc * 64 + i * 16 + fr;
        const int cb = (kk * 64 + fq * 16) ^ ((br & 7) << 4);
        fz[i] = *(const bf16x8*)((const char*)Bz + br * 128 + cb);
        fh[i] = *(const bf16x8*)((const char*)Bh + br * 128 + cb);
      }
#pragma unroll
      for (int i = 0; i < 4; ++i)
#pragma unroll
        for (int j = 0; j < 4; ++j) {
          accz[i][j] = __builtin_amdgcn_mfma_f32_16x16x32_bf16(fa[i], fz[j], accz[i][j], 0, 0, 0);
          acch[i][j] = __builtin_amdgcn_mfma_f32_16x16x32_bf16(fa[i], fh[j], acch[i][j], 0, 0, 0);
        }
    }
  }

  // ===== epilogue: packed c/g + in-register chunk scan.
  // wave wr owns chunk ch = (mt&31)*2 + wr of batch b = mt>>5;
  // row-in-chunk t = i*16 + fq*4 + rg.
  const int b  = mt >> 5;
  const int ch = (mt & 31) * 2 + wr;
#pragma unroll
  for (int j = 0; j < 4; ++j) {
    const int n = n0 + wc * 64 + j * 16 + fr;
    const float bz_n = bz[n];
    const float bh_n = bhv[n];
    float psg[4], qsg[4];
#pragma unroll
    for (int i = 0; i < 4; ++i) {
      float p = 1.0f, q = 0.0f;
#pragma unroll
      for (int rg = 0; rg < 4; ++rg) {
        const int m = m0 + wr * 64 + i * 16 + fq * 4 + rg;
        const float kv = accz[i][j][rg] + bz_n;
        const float av = acch[i][j][rg] + bh_n;
        const float c = 1.0f / (1.0f + expf(kv));
        const float g = (av >= 0.0f) ? (av + 0.5f) : (1.0f / (1.0f + expf(-av)));
        cgbuf[(size_t)m * cH + n] = ((uint32_t)f2bf(g) << 16) | (uint32_t)f2bf(c);
        q = c * q + (1.0f - c) * g;   // compose step (c,(1-c)g) ∘ (p,q)
        p = c * p;
      }
      // cross-fq ordered compose (lanes fq*16+fr; partner masks 16,32)
      float pp = __shfl_xor(p, 16), qq = __shfl_xor(q, 16);
      if (fq & 1) { q = q + p * qq; } else { q = qq + pp * q; }
      p = p * pp;
      pp = __shfl_xor(p, 32); qq = __shfl_xor(q, 32);
      if (fq & 2) { q = q + p * qq; } else { q = qq + pp * q; }
      p = p * pp;
      psg[i] = p; qsg[i] = q;
    }
    float P = psg[0], Q = qsg[0];
#pragma unroll
    for (int i = 1; i < 4; ++i) { Q = qsg[i] + psg[i] * Q; P = psg[i] * P; }
    if (fq == 0) {
      const size_t o = ((size_t)b * NCH + ch) * cH + n;
      Pb[o] = P; Qb[o] = Q;
    }
  }
}

// ======= wave-parallel chunk-prefix: Kogge-Stone compose-scan over 64 chunks.
__global__ void scan_prefix_kernel(const float* __restrict__ h0,
                                   const float* __restrict__ Pb, const float* __restrict__ Qb,
                                   float* __restrict__ hin) {
  const int wid  = (blockIdx.x * blockDim.x + threadIdx.x) >> 6;  // 0..4095
  const int lane = threadIdx.x & 63;
  const int b = wid >> 10, h = wid & 1023;
  const size_t o = ((size_t)b * NCH + lane) * cH + h;
  float P = Pb[o], Q = Qb[o];
#pragma unroll
  for (int off = 1; off < 64; off <<= 1) {
    float Po = __shfl_up(P, off), Qo = __shfl_up(Q, off);
    if (lane >= off) { Q = P * Qo + Q; P = P * Po; }
  }
  float Pe = __shfl_up(P, 1), Qe = __shfl_up(Q, 1);
  if (lane == 0) { Pe = 1.0f; Qe = 0.0f; }
  const float x = h0[b * cH + h];
  const float h0g = (x >= 0.0f) ? (x + 0.5f) : (1.0f / (1.0f + expf(-x)));  // g(h0)
  hin[o] = Pe * h0g + Qe;
}

__global__ void scan_write_kernel(const unsigned int* __restrict__ cg,
                                  const float* __restrict__ hin, float* __restrict__ out) {
  const int bc = blockIdx.x;
  const int b = bc / NCH, ch = bc % NCH;
  const int h4 = threadIdx.x * 4;
  f32x4 hc = *(const f32x4*)(hin + ((size_t)b * NCH + ch) * cH + h4);
  size_t base = ((size_t)b * cS + (size_t)ch * CLEN) * cH + h4;
#pragma unroll 4
  for (int i = 0; i < CLEN; ++i) {
    u32x4 v = *(const u32x4*)(cg + base + (size_t)i * cH);
#pragma unroll
    for (int j = 0; j < 4; ++j) {
      const float c = bf2f((unsigned short)(v[j] & 0xFFFFu));
      const float g = bf2f((unsigned short)(v[j] >> 16));
      hc[j] = c * hc[j] + (1.0f - c) * g;
    }
    *(f32x4*)(out + base + (size_t)i * cH) = hc;
  }
  if (ch == NCH - 1) {
    *(f32x4*)(out + (size_t)cM * cH + (size_t)b * cH + h4) = hc;
  }
}

extern "C" void kernel_launch(void* const* d_in, const int* in_sizes, int n_in,
                              void* d_out, int out_size, void* d_ws, size_t ws_size,
                              hipStream_t stream) {
  const float* x   = (const float*)d_in[0];
  const float* h0  = (const float*)d_in[1];
  const float* Wz  = (const float*)d_in[2];
  const float* bz  = (const float*)d_in[3];
  const float* Wh  = (const float*)d_in[4];
  const float* bh  = (const float*)d_in[5];

  char* ws = (char*)d_ws;
  unsigned short* wwh  = (unsigned short*)(ws + (((size_t)32) << 20));  // 4 MiB
  unsigned int*   cgbuf= (unsigned int*)(ws + (((size_t)40) << 20));    // 64 MiB
  float* Pb   = (float*)(ws + (((size_t)104) << 20));                   // 1 MiB
  float* Qb   = (float*)(ws + (((size_t)105) << 20));                   // 1 MiB
  float* hin  = (float*)(ws + (((size_t)106) << 20));                   // 1 MiB
  float* out  = (float*)d_out;

  round_kernel<<<cH * cK / 1024, 256, 0, stream>>>(Wz, wwh);
  round_kernel<<<cH * cK / 1024, 256, 0, stream>>>(Wh, wwh + (size_t)cH * cK);
  gemm_kernel<<<(cM / BM) * (cH / BN), 256, 0, stream>>>(x, wwh, bz, bh, cgbuf, Pb, Qb);
  scan_prefix_kernel<<<cB * cH * 64 / 256, 256, 0, stream>>>(h0, Pb, Qb, hin);
  scan_write_kernel<<<cB * NCH, 256, 0, stream>>>(cgbuf, hin, out);
}

// Round 15
// 126.279 us; speedup vs baseline: 1.2237x; 1.0987x over previous
//
#include <hip/hip_runtime.h>
#include <hip/hip_bf16.h>
#include <stdint.h>

typedef __attribute__((ext_vector_type(4))) float f32x4;
typedef __attribute__((ext_vector_type(8))) short bf16x8;
typedef __attribute__((ext_vector_type(4))) unsigned short u16x4;
typedef __attribute__((ext_vector_type(4))) unsigned int u32x4;

constexpr int cB = 4, cS = 4096, cD = 1024, cH = 1024;
constexpr int cM = cB * cS;      // 16384
constexpr int cK = cD;           // 1024
constexpr int NCH = 64;          // scan chunks along S
constexpr int CLEN = cS / NCH;   // 64

__device__ __forceinline__ unsigned short f2bf(float f) {
  union { float f; uint32_t u; } v; v.f = f;
  uint32_t r = v.u + 0x7FFFu + ((v.u >> 16) & 1u);
  return (unsigned short)(r >> 16);
}
__device__ __forceinline__ float bf2f(unsigned short h) {
  union { float f; uint32_t u; } v; v.u = ((uint32_t)h) << 16;
  return v.f;
}
// packed RNE f32x2 -> bf16x2 via the COMPILER intrinsic (R14 post-mortem: the
// hand-written v_cvt_pk_bf16_f32 asm had wrong operand-order semantics ->
// c/g halves swapped -> scan multiplied by g>1 -> 1e13 blowup). x->low, y->high.
__device__ __forceinline__ uint32_t pk2(float lo, float hi) {
  __hip_bfloat162 t = __float22bfloat162_rn(make_float2(lo, hi));
  union { __hip_bfloat162 b; uint32_t u; } v; v.b = t;
  return v.u;
}

// fp32 -> bf16 round (W only; x is rounded in-GEMM — R12)
__global__ void round_kernel(const float* __restrict__ src,
                             unsigned short* __restrict__ hi) {
  int i = (blockIdx.x * blockDim.x + threadIdx.x) * 4;
  f32x4 x = *(const f32x4*)(src + i);
  u16x4 h;
#pragma unroll
  for (int j = 0; j < 4; ++j) h[j] = f2bf(x[j]);
  *(u16x4*)(hi + i) = h;
}

// ======= fused GEMM + chunk-scan epilogue.
// R8 dual-stream; R9 in-reg chunk (P,Q); R10 packed cg; R12 in-GEMM x-round.
// R15: VALU diet via compiler intrinsics — __float22bfloat162_rn for packing
// (emits v_cvt_pk with correct semantics) + __expf (2 instrs vs ~25 libm).
constexpr int BM = 128, BN = 128, BK = 64;

__global__ __launch_bounds__(256, 2) void gemm_kernel(
    const float* __restrict__ xf,
    const unsigned short* __restrict__ wwh,   // [Wz(1024 rows); Wh(1024 rows)]
    const float* __restrict__ bz, const float* __restrict__ bhv,
    unsigned int* __restrict__ cgbuf,
    float* __restrict__ Pb, float* __restrict__ Qb)
{
  __shared__ unsigned short Ah[BM * BK], Bz[BN * BK], Bh[BN * BK];  // 48 KiB
  const int tid  = threadIdx.x;
  const int lane = tid & 63;
  const int wv   = tid >> 6;
  const int wr   = wv >> 1, wc = wv & 1;

  // XCD-chunked mapping (R7: FETCH 245->83 MB). 1024 blocks, 128/XCD.
  const int bid = blockIdx.x;          // 0..1023
  const int xcd = bid & 7;
  const int idx = bid >> 3;            // 0..127 within XCD
  const int mt  = xcd * 16 + (idx >> 3);   // 16 mt-rows per XCD, nt-fastest
  const int nt  = idx & 7;
  const int m0 = mt * BM, n0 = nt * BN;
  const int fr = lane & 15, fq = lane >> 4;

  f32x4 accz[4][4] = {};
  f32x4 acch[4][4] = {};

  // staging: LDS linear dest; source pre-swizzled (rule #21): col ^= (row&7)
  const int srow = tid >> 3;                              // 0..31
  const int scol = (((tid & 7) ^ (srow & 7)) << 3);       // element index

  const float*          gX = xf  + (size_t)m0 * cK;
  const unsigned short* gZ = wwh + (size_t)n0 * cK;
  const unsigned short* gH = wwh + (size_t)(cH + n0) * cK;

  for (int kt = 0; kt < cK / BK; ++kt) {
    const int k0 = kt * BK;
    __syncthreads();
    // B DMAs first; latency hides under the A reg-stage below
#pragma unroll
    for (int r = 0; r < 4; ++r) {
      const int row = r * 32 + srow;
      const int ldsoff = r * 4096 + tid * 16;
      const size_t goff = (size_t)row * cK + k0 + scol;
      __builtin_amdgcn_global_load_lds((const __attribute__((address_space(1))) void*)(gZ + goff),
        (__attribute__((address_space(3))) void*)((char*)Bz + ldsoff), 16, 0, 0);
      __builtin_amdgcn_global_load_lds((const __attribute__((address_space(1))) void*)(gH + goff),
        (__attribute__((address_space(3))) void*)((char*)Bh + ldsoff), 16, 0, 0);
    }
    // A: fp32 -> bf16 reg-stage via __float22bfloat162_rn (RNE, same bits as f2bf)
#pragma unroll
    for (int r = 0; r < 4; ++r) {
      const int row = r * 32 + srow;
      const int ldsoff = r * 4096 + tid * 16;
      const size_t goff = (size_t)row * cK + k0 + scol;
      const f32x4 alo = *(const f32x4*)(gX + goff);
      const f32x4 ahi = *(const f32x4*)(gX + goff + 4);
      u32x4 apk;
      apk[0] = pk2(alo[0], alo[1]);
      apk[1] = pk2(alo[2], alo[3]);
      apk[2] = pk2(ahi[0], ahi[1]);
      apk[3] = pk2(ahi[2], ahi[3]);
      *(u32x4*)((char*)Ah + ldsoff) = apk;
    }
    __syncthreads();
#pragma unroll
    for (int kk = 0; kk < BK / 32; ++kk) {
      bf16x8 fa[4], fz[4], fh[4];
#pragma unroll
      for (int i = 0; i < 4; ++i) {
        const int ar = wr * 64 + i * 16 + fr;
        const int ca = (kk * 64 + fq * 16) ^ ((ar & 7) << 4);   // swizzled read (bytes)
        fa[i] = *(const bf16x8*)((const char*)Ah + ar * 128 + ca);
        const int br = wc * 64 + i * 16 + fr;
        const int cb = (kk * 64 + fq * 16) ^ ((br & 7) << 4);
        fz[i] = *(const bf16x8*)((const char*)Bz + br * 128 + cb);
        fh[i] = *(const bf16x8*)((const char*)Bh + br * 128 + cb);
      }
#pragma unroll
      for (int i = 0; i < 4; ++i)
#pragma unroll
        for (int j = 0; j < 4; ++j) {
          accz[i][j] = __builtin_amdgcn_mfma_f32_16x16x32_bf16(fa[i], fz[j], accz[i][j], 0, 0, 0);
          acch[i][j] = __builtin_amdgcn_mfma_f32_16x16x32_bf16(fa[i], fh[j], acch[i][j], 0, 0, 0);
        }
    }
  }

  // ===== epilogue: packed c/g + fast exp + in-register chunk scan.
  // wave wr owns chunk ch = (mt&31)*2 + wr of batch b = mt>>5;
  // row-in-chunk t = i*16 + fq*4 + rg.
  const int b  = mt >> 5;
  const int ch = (mt & 31) * 2 + wr;
#pragma unroll
  for (int j = 0; j < 4; ++j) {
    const int n = n0 + wc * 64 + j * 16 + fr;
    const float bz_n = bz[n];
    const float bh_n = bhv[n];
    float psg[4], qsg[4];
#pragma unroll
    for (int i = 0; i < 4; ++i) {
      float p = 1.0f, q = 0.0f;
#pragma unroll
      for (int rg = 0; rg < 4; ++rg) {
        const int m = m0 + wr * 64 + i * 16 + fq * 4 + rg;
        const float kv = accz[i][j][rg] + bz_n;
        const float av = acch[i][j][rg] + bh_n;
        const float c = 1.0f / (1.0f + __expf(kv));
        const float g = (av >= 0.0f) ? (av + 0.5f) : (1.0f / (1.0f + __expf(-av)));
        cgbuf[(size_t)m * cH + n] = pk2(c, g);   // lo=c, hi=g
        q = c * q + (1.0f - c) * g;   // compose step (c,(1-c)g) ∘ (p,q)
        p = c * p;
      }
      // cross-fq ordered compose (lanes fq*16+fr; partner masks 16,32)
      float pp = __shfl_xor(p, 16), qq = __shfl_xor(q, 16);
      if (fq & 1) { q = q + p * qq; } else { q = qq + pp * q; }
      p = p * pp;
      pp = __shfl_xor(p, 32); qq = __shfl_xor(q, 32);
      if (fq & 2) { q = q + p * qq; } else { q = qq + pp * q; }
      p = p * pp;
      psg[i] = p; qsg[i] = q;
    }
    float P = psg[0], Q = qsg[0];
#pragma unroll
    for (int i = 1; i < 4; ++i) { Q = qsg[i] + psg[i] * Q; P = psg[i] * P; }
    if (fq == 0) {
      const size_t o = ((size_t)b * NCH + ch) * cH + n;
      Pb[o] = P; Qb[o] = Q;
    }
  }
}

// ======= wave-parallel chunk-prefix: Kogge-Stone compose-scan over 64 chunks.
__global__ void scan_prefix_kernel(const float* __restrict__ h0,
                                   const float* __restrict__ Pb, const float* __restrict__ Qb,
                                   float* __restrict__ hin) {
  const int wid  = (blockIdx.x * blockDim.x + threadIdx.x) >> 6;  // 0..4095
  const int lane = threadIdx.x & 63;
  const int b = wid >> 10, h = wid & 1023;
  const size_t o = ((size_t)b * NCH + lane) * cH + h;
  float P = Pb[o], Q = Qb[o];
#pragma unroll
  for (int off = 1; off < 64; off <<= 1) {
    float Po = __shfl_up(P, off), Qo = __shfl_up(Q, off);
    if (lane >= off) { Q = P * Qo + Q; P = P * Po; }
  }
  float Pe = __shfl_up(P, 1), Qe = __shfl_up(Q, 1);
  if (lane == 0) { Pe = 1.0f; Qe = 0.0f; }
  const float x = h0[b * cH + h];
  const float h0g = (x >= 0.0f) ? (x + 0.5f) : (1.0f / (1.0f + expf(-x)));  // g(h0)
  hin[o] = Pe * h0g + Qe;
}

__global__ void scan_write_kernel(const unsigned int* __restrict__ cg,
                                  const float* __restrict__ hin, float* __restrict__ out) {
  const int bc = blockIdx.x;
  const int b = bc / NCH, ch = bc % NCH;
  const int h4 = threadIdx.x * 4;
  f32x4 hc = *(const f32x4*)(hin + ((size_t)b * NCH + ch) * cH + h4);
  size_t base = ((size_t)b * cS + (size_t)ch * CLEN) * cH + h4;
#pragma unroll 4
  for (int i = 0; i < CLEN; ++i) {
    u32x4 v = *(const u32x4*)(cg + base + (size_t)i * cH);
#pragma unroll
    for (int j = 0; j < 4; ++j) {
      const float c = bf2f((unsigned short)(v[j] & 0xFFFFu));
      const float g = bf2f((unsigned short)(v[j] >> 16));
      hc[j] = c * hc[j] + (1.0f - c) * g;
    }
    *(f32x4*)(out + base + (size_t)i * cH) = hc;
  }
  if (ch == NCH - 1) {
    *(f32x4*)(out + (size_t)cM * cH + (size_t)b * cH + h4) = hc;
  }
}

extern "C" void kernel_launch(void* const* d_in, const int* in_sizes, int n_in,
                              void* d_out, int out_size, void* d_ws, size_t ws_size,
                              hipStream_t stream) {
  const float* x   = (const float*)d_in[0];
  const float* h0  = (const float*)d_in[1];
  const float* Wz  = (const float*)d_in[2];
  const float* bz  = (const float*)d_in[3];
  const float* Wh  = (const float*)d_in[4];
  const float* bh  = (const float*)d_in[5];

  char* ws = (char*)d_ws;
  unsigned short* wwh  = (unsigned short*)(ws + (((size_t)32) << 20));  // 4 MiB
  unsigned int*   cgbuf= (unsigned int*)(ws + (((size_t)40) << 20));    // 64 MiB
  float* Pb   = (float*)(ws + (((size_t)104) << 20));                   // 1 MiB
  float* Qb   = (float*)(ws + (((size_t)105) << 20));                   // 1 MiB
  float* hin  = (float*)(ws + (((size_t)106) << 20));                   // 1 MiB
  float* out  = (float*)d_out;

  round_kernel<<<cH * cK / 1024, 256, 0, stream>>>(Wz, wwh);
  round_kernel<<<cH * cK / 1024, 256, 0, stream>>>(Wh, wwh + (size_t)cH * cK);
  gemm_kernel<<<(cM / BM) * (cH / BN), 256, 0, stream>>>(x, wwh, bz, bh, cgbuf, Pb, Qb);
  scan_prefix_kernel<<<cB * cH * 64 / 256, 256, 0, stream>>>(h0, Pb, Qb, hin);
  scan_write_kernel<<<cB * NCH, 256, 0, stream>>>(cgbuf, hin, out);
}

// Round 16
// 117.552 us; speedup vs baseline: 1.3146x; 1.0742x over previous
//
#include <hip/hip_runtime.h>
#include <hip/hip_bf16.h>
#include <stdint.h>

typedef __attribute__((ext_vector_type(4))) float f32x4;
typedef __attribute__((ext_vector_type(8))) short bf16x8;
typedef __attribute__((ext_vector_type(4))) unsigned short u16x4;
typedef __attribute__((ext_vector_type(4))) unsigned int u32x4;

constexpr int cB = 4, cS = 4096, cD = 1024, cH = 1024;
constexpr int cM = cB * cS;      // 16384
constexpr int cK = cD;           // 1024
constexpr int NCH = 64;          // scan chunks along S
constexpr int CLEN = cS / NCH;   // 64

__device__ __forceinline__ unsigned short f2bf(float f) {
  union { float f; uint32_t u; } v; v.f = f;
  uint32_t r = v.u + 0x7FFFu + ((v.u >> 16) & 1u);
  return (unsigned short)(r >> 16);
}
__device__ __forceinline__ float bf2f(unsigned short h) {
  union { float f; uint32_t u; } v; v.u = ((uint32_t)h) << 16;
  return v.f;
}
// packed RNE f32x2 -> bf16x2 via compiler intrinsic (x->low, y->high).
__device__ __forceinline__ uint32_t pk2(float lo, float hi) {
  __hip_bfloat162 t = __float22bfloat162_rn(make_float2(lo, hi));
  union { __hip_bfloat162 b; uint32_t u; } v; v.b = t;
  return v.u;
}

// fp32 -> bf16 round for BOTH W matrices in one launch (R16: merged)
__global__ void roundW_kernel(const float* __restrict__ wz, const float* __restrict__ wh,
                              unsigned short* __restrict__ dst) {
  const int nb = (cH * cK) / 1024;             // 1024 blocks per matrix
  const int bidx = blockIdx.x;
  const bool second = (bidx >= nb);
  const float* src = second ? wh : wz;
  const int base = ((second ? bidx - nb : bidx) * 256 + threadIdx.x) * 4;
  f32x4 x = *(const f32x4*)(src + base);
  u16x4 h;
#pragma unroll
  for (int j = 0; j < 4; ++j) h[j] = f2bf(x[j]);
  *(u16x4*)(dst + (second ? cH * cK : 0) + base) = h;
}

// ======= fused GEMM + chunk-scan epilogue.
// R8 dual-stream; R9 in-reg chunk (P,Q); R10 packed cg; R12 in-GEMM x-round;
// R15 cvt_pk/__expf. R16: B double-buffer + raw s_barrier (no vmcnt0 drain) —
// B(t+1) DMAs stay in flight across the barrier. In-order vmcnt trick: issue
// A fp32 loads FIRST, then B(t+1) DMAs, then vmcnt(8) => drains own A + own
// B(t), leaves B(t+1)'s 8 outstanding. lgkmcnt(0)+s_barrier makes all waves'
// ds_writes + B(t) landings visible. 2 barriers/tile (same as before),
// LDS 80 KiB x 2 blocks = 160 KiB (full CU pool), occupancy unchanged.
constexpr int BM = 128, BN = 128, BK = 64;
constexpr int NT = cK / BK;   // 16

__global__ __launch_bounds__(256, 2) void gemm_kernel(
    const float* __restrict__ xf,
    const unsigned short* __restrict__ wwh,   // [Wz(1024 rows); Wh(1024 rows)]
    const float* __restrict__ bz, const float* __restrict__ bhv,
    unsigned int* __restrict__ cgbuf,
    float* __restrict__ Pb, float* __restrict__ Qb)
{
  __shared__ unsigned short Ah[BM * BK];        // 16 KiB
  __shared__ unsigned short Bzb[2][BN * BK];    // 32 KiB
  __shared__ unsigned short Bhb[2][BN * BK];    // 32 KiB (80 KiB total)
  const int tid  = threadIdx.x;
  const int lane = tid & 63;
  const int wv   = tid >> 6;
  const int wr   = wv >> 1, wc = wv & 1;

  // XCD-chunked mapping (R7). 1024 blocks, 128/XCD.
  const int bid = blockIdx.x;          // 0..1023
  const int xcd = bid & 7;
  const int idx = bid >> 3;            // 0..127 within XCD
  const int mt  = xcd * 16 + (idx >> 3);   // 16 mt-rows per XCD, nt-fastest
  const int nt  = idx & 7;
  const int m0 = mt * BM, n0 = nt * BN;
  const int fr = lane & 15, fq = lane >> 4;

  f32x4 accz[4][4] = {};
  f32x4 acch[4][4] = {};

  // staging: LDS linear dest; source pre-swizzled (rule #21): col ^= (row&7)
  const int srow = tid >> 3;                              // 0..31
  const int scol = (((tid & 7) ^ (srow & 7)) << 3);       // element index

  const float*          gX = xf  + (size_t)m0 * cK;
  const unsigned short* gZ = wwh + (size_t)n0 * cK;
  const unsigned short* gH = wwh + (size_t)(cH + n0) * cK;

  // prologue: B(0) DMAs into buf 0 (stay in flight; drained by loop's vmcnt(8))
#pragma unroll
  for (int r = 0; r < 4; ++r) {
    const int ldsoff = r * 4096 + tid * 16;
    const size_t goff = (size_t)(r * 32 + srow) * cK + scol;
    __builtin_amdgcn_global_load_lds((const __attribute__((address_space(1))) void*)(gZ + goff),
      (__attribute__((address_space(3))) void*)((char*)Bzb[0] + ldsoff), 16, 0, 0);
    __builtin_amdgcn_global_load_lds((const __attribute__((address_space(1))) void*)(gH + goff),
      (__attribute__((address_space(3))) void*)((char*)Bhb[0] + ldsoff), 16, 0, 0);
  }

  for (int kt = 0; kt < NT; ++kt) {
    const int cur = kt & 1, nxt = cur ^ 1;
    const int k0 = kt * BK;
    // 1. ALL A fp32 loads first (must be older than B(t+1) for the vmcnt trick)
    f32x4 av[8];
#pragma unroll
    for (int r = 0; r < 4; ++r) {
      const size_t goff = (size_t)(r * 32 + srow) * cK + k0 + scol;
      av[2 * r]     = *(const f32x4*)(gX + goff);
      av[2 * r + 1] = *(const f32x4*)(gX + goff + 4);
    }
    // 2. B(t+1) DMAs into the other buffer
    if (kt + 1 < NT) {
      const int kn = k0 + BK;
#pragma unroll
      for (int r = 0; r < 4; ++r) {
        const int ldsoff = r * 4096 + tid * 16;
        const size_t goff = (size_t)(r * 32 + srow) * cK + kn + scol;
        __builtin_amdgcn_global_load_lds((const __attribute__((address_space(1))) void*)(gZ + goff),
          (__attribute__((address_space(3))) void*)((char*)Bzb[nxt] + ldsoff), 16, 0, 0);
        __builtin_amdgcn_global_load_lds((const __attribute__((address_space(1))) void*)(gH + goff),
          (__attribute__((address_space(3))) void*)((char*)Bhb[nxt] + ldsoff), 16, 0, 0);
      }
    }
    // 3. drain own A loads + own B(t); leave B(t+1)'s 8 in flight (in-order)
    asm volatile("s_waitcnt vmcnt(8)" ::: "memory");
    // 4. cvt + ds_write A(t)
#pragma unroll
    for (int r = 0; r < 4; ++r) {
      u32x4 apk;
      apk[0] = pk2(av[2 * r][0], av[2 * r][1]);
      apk[1] = pk2(av[2 * r][2], av[2 * r][3]);
      apk[2] = pk2(av[2 * r + 1][0], av[2 * r + 1][1]);
      apk[3] = pk2(av[2 * r + 1][2], av[2 * r + 1][3]);
      *(u32x4*)((char*)Ah + r * 4096 + tid * 16) = apk;
    }
    // 5. barrier WITHOUT vmcnt0: all waves past their vmcnt(8) => B(t) landed;
    //    lgkmcnt(0) => ds_writes visible.
    asm volatile("s_waitcnt lgkmcnt(0)\n\ts_barrier" ::: "memory");
    // 6. compute tile t
#pragma unroll
    for (int kk = 0; kk < BK / 32; ++kk) {
      bf16x8 fa[4], fz[4], fh[4];
#pragma unroll
      for (int i = 0; i < 4; ++i) {
        const int ar = wr * 64 + i * 16 + fr;
        const int ca = (kk * 64 + fq * 16) ^ ((ar & 7) << 4);   // swizzled read (bytes)
        fa[i] = *(const bf16x8*)((const char*)Ah + ar * 128 + ca);
        const int br = wc * 64 + i * 16 + fr;
        const int cb = (kk * 64 + fq * 16) ^ ((br & 7) << 4);
        fz[i] = *(const bf16x8*)((const char*)Bzb[cur] + br * 128 + cb);
        fh[i] = *(const bf16x8*)((const char*)Bhb[cur] + br * 128 + cb);
      }
#pragma unroll
      for (int i = 0; i < 4; ++i)
#pragma unroll
        for (int j = 0; j < 4; ++j) {
          accz[i][j] = __builtin_amdgcn_mfma_f32_16x16x32_bf16(fa[i], fz[j], accz[i][j], 0, 0, 0);
          acch[i][j] = __builtin_amdgcn_mfma_f32_16x16x32_bf16(fa[i], fh[j], acch[i][j], 0, 0, 0);
        }
    }
    // 7. end-of-tile barrier: all reads of Ah/Bb[cur] complete (data-dep)
    //    before next iter overwrites Ah / DMA-writes Bb[cur].
    asm volatile("s_barrier" ::: "memory");
  }

  // ===== epilogue: packed c/g + fast exp/rcp + in-register chunk scan.
  // wave wr owns chunk ch = (mt&31)*2 + wr of batch b = mt>>5;
  // row-in-chunk t = i*16 + fq*4 + rg.
  const int b  = mt >> 5;
  const int ch = (mt & 31) * 2 + wr;
#pragma unroll
  for (int j = 0; j < 4; ++j) {
    const int n = n0 + wc * 64 + j * 16 + fr;
    const float bz_n = bz[n];
    const float bh_n = bhv[n];
    float psg[4], qsg[4];
#pragma unroll
    for (int i = 0; i < 4; ++i) {
      float p = 1.0f, q = 0.0f;
#pragma unroll
      for (int rg = 0; rg < 4; ++rg) {
        const int m = m0 + wr * 64 + i * 16 + fq * 4 + rg;
        const float kv = accz[i][j][rg] + bz_n;
        const float av2 = acch[i][j][rg] + bh_n;
        const float c = __builtin_amdgcn_rcpf(1.0f + __expf(kv));
        const float g = (av2 >= 0.0f) ? (av2 + 0.5f)
                                      : __builtin_amdgcn_rcpf(1.0f + __expf(-av2));
        cgbuf[(size_t)m * cH + n] = pk2(c, g);   // lo=c, hi=g
        q = c * q + (1.0f - c) * g;   // compose step (c,(1-c)g) ∘ (p,q)
        p = c * p;
      }
      // cross-fq ordered compose (lanes fq*16+fr; partner masks 16,32)
      float pp = __shfl_xor(p, 16), qq = __shfl_xor(q, 16);
      if (fq & 1) { q = q + p * qq; } else { q = qq + pp * q; }
      p = p * pp;
      pp = __shfl_xor(p, 32); qq = __shfl_xor(q, 32);
      if (fq & 2) { q = q + p * qq; } else { q = qq + pp * q; }
      p = p * pp;
      psg[i] = p; qsg[i] = q;
    }
    float P = psg[0], Q = qsg[0];
#pragma unroll
    for (int i = 1; i < 4; ++i) { Q = qsg[i] + psg[i] * Q; P = psg[i] * P; }
    if (fq == 0) {
      const size_t o = ((size_t)b * NCH + ch) * cH + n;
      Pb[o] = P; Qb[o] = Q;
    }
  }
}

// ======= wave-parallel chunk-prefix: Kogge-Stone compose-scan over 64 chunks.
__global__ void scan_prefix_kernel(const float* __restrict__ h0,
                                   const float* __restrict__ Pb, const float* __restrict__ Qb,
                                   float* __restrict__ hin) {
  const int wid  = (blockIdx.x * blockDim.x + threadIdx.x) >> 6;  // 0..4095
  const int lane = threadIdx.x & 63;
  const int b = wid >> 10, h = wid & 1023;
  const size_t o = ((size_t)b * NCH + lane) * cH + h;
  float P = Pb[o], Q = Qb[o];
#pragma unroll
  for (int off = 1; off < 64; off <<= 1) {
    float Po = __shfl_up(P, off), Qo = __shfl_up(Q, off);
    if (lane >= off) { Q = P * Qo + Q; P = P * Po; }
  }
  float Pe = __shfl_up(P, 1), Qe = __shfl_up(Q, 1);
  if (lane == 0) { Pe = 1.0f; Qe = 0.0f; }
  const float x = h0[b * cH + h];
  const float h0g = (x >= 0.0f) ? (x + 0.5f) : (1.0f / (1.0f + expf(-x)));  // g(h0)
  hin[o] = Pe * h0g + Qe;
}

__global__ void scan_write_kernel(const unsigned int* __restrict__ cg,
                                  const float* __restrict__ hin, float* __restrict__ out) {
  const int bc = blockIdx.x;
  const int b = bc / NCH, ch = bc % NCH;
  const int h4 = threadIdx.x * 4;
  f32x4 hc = *(const f32x4*)(hin + ((size_t)b * NCH + ch) * cH + h4);
  size_t base = ((size_t)b * cS + (size_t)ch * CLEN) * cH + h4;
#pragma unroll 4
  for (int i = 0; i < CLEN; ++i) {
    u32x4 v = *(const u32x4*)(cg + base + (size_t)i * cH);
#pragma unroll
    for (int j = 0; j < 4; ++j) {
      const float c = bf2f((unsigned short)(v[j] & 0xFFFFu));
      const float g = bf2f((unsigned short)(v[j] >> 16));
      hc[j] = c * hc[j] + (1.0f - c) * g;
    }
    *(f32x4*)(out + base + (size_t)i * cH) = hc;
  }
  if (ch == NCH - 1) {
    *(f32x4*)(out + (size_t)cM * cH + (size_t)b * cH + h4) = hc;
  }
}

extern "C" void kernel_launch(void* const* d_in, const int* in_sizes, int n_in,
                              void* d_out, int out_size, void* d_ws, size_t ws_size,
                              hipStream_t stream) {
  const float* x   = (const float*)d_in[0];
  const float* h0  = (const float*)d_in[1];
  const float* Wz  = (const float*)d_in[2];
  const float* bz  = (const float*)d_in[3];
  const float* Wh  = (const float*)d_in[4];
  const float* bh  = (const float*)d_in[5];

  char* ws = (char*)d_ws;
  unsigned short* wwh  = (unsigned short*)(ws + (((size_t)32) << 20));  // 4 MiB
  unsigned int*   cgbuf= (unsigned int*)(ws + (((size_t)40) << 20));    // 64 MiB
  float* Pb   = (float*)(ws + (((size_t)104) << 20));                   // 1 MiB
  float* Qb   = (float*)(ws + (((size_t)105) << 20));                   // 1 MiB
  float* hin  = (float*)(ws + (((size_t)106) << 20));                   // 1 MiB
  float* out  = (float*)d_out;

  roundW_kernel<<<2 * cH * cK / 1024, 256, 0, stream>>>(Wz, Wh, wwh);
  gemm_kernel<<<(cM / BM) * (cH / BN), 256, 0, stream>>>(x, wwh, bz, bh, cgbuf, Pb, Qb);
  scan_prefix_kernel<<<cB * cH * 64 / 256, 256, 0, stream>>>(h0, Pb, Qb, hin);
  scan_write_kernel<<<cB * NCH, 256, 0, stream>>>(cgbuf, hin, out);
}